// Round 1
// 1220.411 us; speedup vs baseline: 1.5930x; 1.5930x over previous
//
#include <hip/hip_runtime.h>

typedef unsigned short u16;
typedef __bf16 bf16x8 __attribute__((ext_vector_type(8)));
typedef float f32x4 __attribute__((ext_vector_type(4)));

#define NEXP 30
#define INSZ 1024
#define HID 2048
#define NB 8192

// ---------- helpers ----------
__device__ __forceinline__ u16 f2bf(float f) {
    union { float f; unsigned u; } x; x.f = f;
    unsigned r = x.u + 0x7FFFu + ((x.u >> 16) & 1u);   // RNE
    return (u16)(r >> 16);
}

typedef __attribute__((address_space(3))) unsigned int lds_u32;
typedef const __attribute__((address_space(1))) unsigned int glb_u32;
__device__ __forceinline__ void gl2lds16(const void* g, void* l) {
    // async global->LDS, 16B per lane; LDS dest must be wave-uniform base + lane*16
    __builtin_amdgcn_global_load_lds((glb_u32*)g, (lds_u32*)l, 16, 0, 0);
}

struct alignas(16) U16x8 { u16 v[8]; };

// ---------- conversion: x fp32 -> bf16 (same layout) ----------
__global__ __launch_bounds__(256) void conv_x(const float* __restrict__ in,
                                              u16* __restrict__ out) {
    size_t base = ((size_t)blockIdx.x * 256 + threadIdx.x) * 8;
    float4 v0 = *(const float4*)(in + base);
    float4 v1 = *(const float4*)(in + base + 4);
    U16x8 o;
    o.v[0] = f2bf(v0.x); o.v[1] = f2bf(v0.y); o.v[2] = f2bf(v0.z); o.v[3] = f2bf(v0.w);
    o.v[4] = f2bf(v1.x); o.v[5] = f2bf(v1.y); o.v[6] = f2bf(v1.z); o.v[7] = f2bf(v1.w);
    *(U16x8*)(out + base) = o;
}

// ---------- conversion: W1 [E][I][H] fp32 -> Wt [E][H][I] bf16 (tiled transpose) ----------
__global__ __launch_bounds__(256) void conv_w1(const float* __restrict__ W1,
                                               u16* __restrict__ Wt) {
    __shared__ float t[32][33];
    const int e  = blockIdx.z;
    const int h0 = blockIdx.x * 32;
    const int i0 = blockIdx.y * 32;
    const int tx = threadIdx.x, ty = threadIdx.y;   // 32 x 8
    const float* src = W1 + (size_t)e * INSZ * HID;
    u16* dst = Wt + (size_t)e * HID * INSZ;
    #pragma unroll
    for (int j = 0; j < 32; j += 8)
        t[ty + j][tx] = src[(size_t)(i0 + ty + j) * HID + h0 + tx];
    __syncthreads();
    #pragma unroll
    for (int j = 0; j < 32; j += 8)
        dst[(size_t)(h0 + ty + j) * INSZ + i0 + tx] = f2bf(t[tx][ty + j]);
}

// ---------- fused fc1(MFMA bf16) + ReLU + fc2 + sigmoid + mean ----------
// 256x256 tile, BK=32, 8 waves (2M x 4N), 4-slot LDS ring, counted vmcnt(8),
// XOR-swizzled LDS (pre-swizzled global source + swizzled ds_read), setprio
// around MFMA clusters. Flat 256-tile pipeline across the 8 n-tiles.
__global__ __launch_bounds__(512, 2) void fused_mlp(
        const u16* __restrict__ Xb,   // [NB][INSZ] bf16
        const u16* __restrict__ Wt,   // [E][HID][INSZ] bf16
        const float* __restrict__ b1, // [E][HID]
        const float* __restrict__ W2, // [E][HID]
        const float* __restrict__ b2, // [E]
        float* __restrict__ out)      // [NB]
{
    // 4 ring slots x (A 256x32 + B 256x32) bf16 = 128 KiB exactly
    __shared__ __attribute__((aligned(16))) u16 smem[4][2][8192];

    const int e     = blockIdx.y;
    const int mbase = blockIdx.x * 256;
    const int tid   = threadIdx.x;      // 0..511
    const int lane  = tid & 63;
    const int wid   = tid >> 6;         // 0..7
    const int q     = lane >> 4;        // k-slice quad
    const int c     = lane & 15;        // row/col within frag
    const int wr    = wid >> 2;         // 0..1 : 128-row half
    const int wc    = wid & 3;          // 0..3 : 64-col quarter

    // staging: thread -> row tid/4 (within 128-row part), 16B piece (tid&3)
    const int srow  = tid >> 2;                               // 0..127
    const int kswz  = ((tid & 3) ^ ((tid >> 3) & 3)) * 8;     // pre-swizzled global k (u16)
    const int kread = (q ^ ((c >> 1) & 3)) * 8;               // swizzled read k (u16)

    const u16* xA0 = Xb + (size_t)(mbase + srow) * INSZ + kswz;
    const u16* xA1 = xA0 + (size_t)128 * INSZ;
    const u16* wB0 = Wt + (size_t)e * HID * INSZ + (size_t)srow * INSZ + kswz;
    const float* b1e = b1 + e * HID;
    const float* w2e = W2 + e * HID;

    const int aoff = (wr * 128 + c) * 32 + kread;   // u16 index into A slot
    const int boff = (wc * 64 + c) * 32 + kread;    // u16 index into B slot

    f32x4 acc[8][4];
    float rowacc[8][4];
    #pragma unroll
    for (int mi = 0; mi < 8; mi++)
        #pragma unroll
        for (int ni = 0; ni < 4; ni++)
            acc[mi][ni] = f32x4{0.f, 0.f, 0.f, 0.f};
    #pragma unroll
    for (int mi = 0; mi < 8; mi++)
        #pragma unroll
        for (int r = 0; r < 4; r++) rowacc[mi][r] = 0.f;

#define STAGE_A(S, KT) do { \
        gl2lds16(xA0 + (KT) * 32, &smem[S][0][tid * 8]); \
        gl2lds16(xA1 + (KT) * 32, &smem[S][0][4096 + tid * 8]); \
    } while (0)
#define STAGE_B(S, NT, KT) do { \
        const u16* _b = wB0 + (size_t)(NT) * (256 * INSZ) + (KT) * 32; \
        gl2lds16(_b, &smem[S][1][tid * 8]); \
        gl2lds16(_b + 128 * INSZ, &smem[S][1][4096 + tid * 8]); \
    } while (0)

    // prologue: stage tiles 0,1,2 (flat tile t = nt*32+kt, slot = t&3)
    STAGE_A(0, 0); STAGE_B(0, 0, 0);
    STAGE_A(1, 1); STAGE_B(1, 0, 1);
    STAGE_A(2, 2); STAGE_B(2, 0, 2);

    #pragma unroll 1
    for (int nt = 0; nt < 8; ++nt) {
        // hoist epilogue operands so their wait-for-use never drains the pipe
        float bb[4], ww[4];
        #pragma unroll
        for (int ni = 0; ni < 4; ni++) {
            const int n = nt * 256 + wc * 64 + ni * 16 + c;
            bb[ni] = b1e[n];
            ww[ni] = w2e[n];
        }
        #pragma unroll 4
        for (int kt = 0; kt < 32; ++kt) {
            const int slot = kt & 3;
            const int s3   = (kt + 3) & 3;      // staging slot: always (t+3)&3
            int tc = nt * 32 + kt + 3;
            if (tc > 255) tc = 255;             // tail: dead re-stage of tile 255 into free slot
            const int nt3 = tc >> 5;
            const int kt3 = tc & 31;

            // tile boundary: own stage loads for tile t landed (8 newer allowed),
            // own ds_reads drained, then barrier -> ALL waves' loads landed.
            asm volatile("s_waitcnt vmcnt(8) lgkmcnt(0)" ::: "memory");
            __builtin_amdgcn_s_barrier();
            __builtin_amdgcn_sched_barrier(0);

            const u16* As = &smem[slot][0][0];
            const u16* Bs = &smem[slot][1][0];

            // phase A: lower 64 rows + all B frags
            bf16x8 af[4], bv[4];
            #pragma unroll
            for (int mi = 0; mi < 4; mi++)
                af[mi] = *(const bf16x8*)(As + aoff + mi * 512);
            #pragma unroll
            for (int ni = 0; ni < 4; ni++)
                bv[ni] = *(const bf16x8*)(Bs + boff + ni * 512);

            STAGE_A(s3, kt3);
            __builtin_amdgcn_s_barrier();

            __builtin_amdgcn_s_setprio(1);
            #pragma unroll
            for (int mi = 0; mi < 4; mi++)
                #pragma unroll
                for (int ni = 0; ni < 4; ni++)
                    acc[mi][ni] = __builtin_amdgcn_mfma_f32_16x16x32_bf16(
                        af[mi], bv[ni], acc[mi][ni], 0, 0, 0);
            __builtin_amdgcn_s_setprio(0);

            // phase B: upper 64 rows, reuse bv
            bf16x8 af2[4];
            #pragma unroll
            for (int mi = 0; mi < 4; mi++)
                af2[mi] = *(const bf16x8*)(As + aoff + 2048 + mi * 512);

            STAGE_B(s3, nt3, kt3);
            __builtin_amdgcn_s_barrier();

            __builtin_amdgcn_s_setprio(1);
            #pragma unroll
            for (int mi = 0; mi < 4; mi++)
                #pragma unroll
                for (int ni = 0; ni < 4; ni++)
                    acc[4 + mi][ni] = __builtin_amdgcn_mfma_f32_16x16x32_bf16(
                        af2[mi], bv[ni], acc[4 + mi][ni], 0, 0, 0);
            __builtin_amdgcn_s_setprio(0);
        }

        // epilogue: +b1, ReLU, *W2, accumulate per-row; reset acc
        #pragma unroll
        for (int ni = 0; ni < 4; ni++)
            #pragma unroll
            for (int mi = 0; mi < 8; mi++)
                #pragma unroll
                for (int r = 0; r < 4; r++) {
                    float v = fmaxf(acc[mi][ni][r] + bb[ni], 0.f);
                    rowacc[mi][r] = fmaf(v, ww[ni], rowacc[mi][r]);
                    acc[mi][ni][r] = 0.f;
                }
    }

    // drain everything (incl. dead tail stages) before reusing LDS
    asm volatile("s_waitcnt vmcnt(0)" ::: "memory");
    __syncthreads();
    float* rsum = (float*)&smem[0][0][0];
    if (tid < 256) rsum[tid] = 0.f;
    __syncthreads();
    #pragma unroll
    for (int mi = 0; mi < 8; mi++)
        #pragma unroll
        for (int r = 0; r < 4; r++) {
            float v = rowacc[mi][r];
            v += __shfl_xor(v, 1); v += __shfl_xor(v, 2);
            v += __shfl_xor(v, 4); v += __shfl_xor(v, 8);
            if (c == 0) atomicAdd(&rsum[wr * 128 + mi * 16 + q * 4 + r], v);
        }
    __syncthreads();
    if (tid < 256) {
        float z = rsum[tid] + b2[e];
        float s = 1.f / (1.f + __expf(-z));
        atomicAdd(&out[mbase + tid], s * (1.0f / NEXP));
    }
#undef STAGE_A
#undef STAGE_B
}

// ---------- slow-but-correct fallback (only if ws too small) ----------
__global__ __launch_bounds__(256) void fallback_kernel(
        const float* __restrict__ x, const float* __restrict__ W1,
        const float* __restrict__ b1, const float* __restrict__ W2,
        const float* __restrict__ b2, float* __restrict__ out)
{
    __shared__ float xs[64 * 128];   // 32 KB
    __shared__ float zsum[64];
    const int e  = blockIdx.y;
    const int r0 = blockIdx.x * 64;
    const int tid = threadIdx.x;
    if (tid < 64) zsum[tid] = 0.f;
    const float* W1e = W1 + (size_t)e * INSZ * HID;

    for (int hg = 0; hg < 8; hg++) {
        const int h = hg * 256 + tid;
        float acc[64];
        #pragma unroll
        for (int r = 0; r < 64; r++) acc[r] = 0.f;
        for (int ic = 0; ic < 8; ic++) {
            __syncthreads();
            for (int t = tid; t < 64 * 128; t += 256) {
                int r = t >> 7, i = t & 127;
                xs[t] = x[(size_t)(r0 + r) * INSZ + ic * 128 + i];
            }
            __syncthreads();
            for (int i = 0; i < 128; i++) {
                float wv = W1e[(size_t)(ic * 128 + i) * HID + h];
                #pragma unroll
                for (int r = 0; r < 64; r++)
                    acc[r] = fmaf(xs[r * 128 + i], wv, acc[r]);
            }
        }
        const float bb = b1[e * HID + h];
        const float ww = W2[e * HID + h];
        #pragma unroll
        for (int r = 0; r < 64; r++) {
            float v = fmaxf(acc[r] + bb, 0.f) * ww;
            v += __shfl_xor(v, 1);  v += __shfl_xor(v, 2);  v += __shfl_xor(v, 4);
            v += __shfl_xor(v, 8);  v += __shfl_xor(v, 16); v += __shfl_xor(v, 32);
            if ((tid & 63) == 0) atomicAdd(&zsum[r], v);
        }
    }
    __syncthreads();
    if (tid < 64) {
        float z = zsum[tid] + b2[e];
        atomicAdd(&out[r0 + tid], (1.f / (1.f + __expf(-z))) * (1.0f / NEXP));
    }
}

extern "C" void kernel_launch(void* const* d_in, const int* in_sizes, int n_in,
                              void* d_out, int out_size, void* d_ws, size_t ws_size,
                              hipStream_t stream) {
    const float* x  = (const float*)d_in[0];
    const float* W1 = (const float*)d_in[1];
    const float* b1 = (const float*)d_in[2];
    const float* W2 = (const float*)d_in[3];
    const float* b2 = (const float*)d_in[4];
    float* out = (float*)d_out;

    hipMemsetAsync(out, 0, (size_t)out_size * sizeof(float), stream);

    const size_t xb_bytes = (size_t)NB * INSZ * sizeof(u16);          // 16 MB
    const size_t wt_bytes = (size_t)NEXP * HID * INSZ * sizeof(u16);  // 126 MB
    if (ws_size >= xb_bytes + wt_bytes) {
        u16* Xb = (u16*)d_ws;
        u16* Wt = (u16*)((char*)d_ws + xb_bytes);
        conv_x<<<dim3((NB * INSZ) / 2048), 256, 0, stream>>>(x, Xb);
        conv_w1<<<dim3(HID / 32, INSZ / 32, NEXP), dim3(32, 8), 0, stream>>>(W1, Wt);
        fused_mlp<<<dim3(NB / 256, NEXP), 512, 0, stream>>>(Xb, Wt, b1, W2, b2, out);
    } else {
        fallback_kernel<<<dim3(NB / 64, NEXP), 256, 0, stream>>>(x, W1, b1, W2, b2, out);
    }
}